// Round 1
// baseline (1748.369 us; speedup 1.0000x reference)
//
#include <hip/hip_runtime.h>
#include <math.h>

#define BB 8
#define NN 4096
#define DIMc 256
#define HH 8
#define DH 64
#define INNERc 512

// ---------- bf16 helpers on plain ushort (avoid union-with-class issues) ----------
static __device__ __forceinline__ unsigned short f2bf(float f) {
    union { float f; unsigned int u; } c; c.f = f;
    unsigned int u = c.u;
    unsigned int r = (u + 0x7fffu + ((u >> 16) & 1u)) >> 16;  // RNE
    return (unsigned short)r;
}
static __device__ __forceinline__ float bf2f(unsigned short s) {
    union { unsigned int u; float f; } c; c.u = ((unsigned int)s) << 16;
    return c.f;
}

// =====================================================================
// Kernel 1: kv = z @ Wkv ; split k,v ; instance-norm(64) ; rotary(k,z_pos)
// Each thread owns one (row, head-slot): slot<8 -> k head, slot>=8 -> v head.
// Block: 256 threads, 32 rows of z (2 passes of 16 rows x 16 slots).
// =====================================================================
__global__ __launch_bounds__(256) void kv_kernel(
    const float* __restrict__ z, const float* __restrict__ z_pos,
    const float* __restrict__ Wkv,
    unsigned short* __restrict__ Kbuf, unsigned short* __restrict__ Vbuf)
{
    __shared__ float zt[32 * 260];   // padded: bank-spread for zt[row][kk] reads
    const int blk = blockIdx.x;
    const int b  = blk >> 7;            // / (NN/32)=128
    const int r0 = (blk & 127) << 5;    // * 32
    const int tid = threadIdx.x;

    const float4* zg = (const float4*)(z + ((size_t)b * NN + r0) * DIMc);
    for (int i = tid; i < 32 * 64; i += 256) {
        int r = i >> 6, c4 = i & 63;
        *((float4*)&zt[r * 260 + c4 * 4]) = zg[i];
    }
    __syncthreads();

    const int slot = tid >> 4;   // 0..15
    const int rloc = tid & 15;   // 0..15

    for (int pass = 0; pass < 2; ++pass) {
        const int row = pass * 16 + rloc;
        const float* zr = &zt[row * 260];
        float acc[64];
        #pragma unroll
        for (int j = 0; j < 64; ++j) acc[j] = 0.f;

        for (int kk = 0; kk < DIMc; ++kk) {
            const float zv = zr[kk];
            const float4* w = (const float4*)(Wkv + (size_t)kk * 1024 + slot * 64);
            #pragma unroll
            for (int j = 0; j < 16; ++j) {
                float4 wv = w[j];
                acc[4*j+0] = fmaf(zv, wv.x, acc[4*j+0]);
                acc[4*j+1] = fmaf(zv, wv.y, acc[4*j+1]);
                acc[4*j+2] = fmaf(zv, wv.z, acc[4*j+2]);
                acc[4*j+3] = fmaf(zv, wv.w, acc[4*j+3]);
            }
        }

        // instance norm over the 64 head elements (biased var, eps inside rsqrt)
        float mu = 0.f;
        #pragma unroll
        for (int j = 0; j < 64; ++j) mu += acc[j];
        mu *= (1.f / 64.f);
        float var = 0.f;
        #pragma unroll
        for (int j = 0; j < 64; ++j) { float d = acc[j] - mu; var = fmaf(d, d, var); }
        var *= (1.f / 64.f);
        const float rs = rsqrtf(var + 1e-5f);
        #pragma unroll
        for (int j = 0; j < 64; ++j) acc[j] = (acc[j] - mu) * rs;

        const int n = r0 + row;
        const bool isK = (slot < 8);
        const int h = isK ? slot : (slot - 8);
        unsigned short* outp = (isK ? Kbuf : Vbuf) + (((size_t)b * HH + h) * NN + n) * DH;

        if (isK) {
            const float px = z_pos[((size_t)b * NN + n) * 2 + 0] * 64.f;
            const float py = z_pos[((size_t)b * NN + n) * 2 + 1] * 64.f;
            float rot[64];
            #pragma unroll
            for (int j = 0; j < 16; ++j) {
                const float invf = exp2f((float)j * -0.83048202f); // 10000^(-j/16)
                float sx, cx, sy, cy;
                sincosf(px * invf, &sx, &cx);
                sincosf(py * invf, &sy, &cy);
                rot[j]      = acc[j]      * cx - acc[j + 16] * sx;
                rot[j + 16] = acc[j + 16] * cx + acc[j]      * sx;
                rot[32 + j] = acc[32 + j] * cy - acc[48 + j] * sy;
                rot[48 + j] = acc[48 + j] * cy + acc[32 + j] * sy;
            }
            #pragma unroll
            for (int j = 0; j < 64; ++j) acc[j] = rot[j];
        }

        // pack to bf16, 16B stores
        uint4* o4 = (uint4*)outp;
        #pragma unroll
        for (int g = 0; g < 8; ++g) {
            union { uint4 u; unsigned short s[8]; } pk;
            #pragma unroll
            for (int j = 0; j < 8; ++j) pk.s[j] = f2bf(acc[g * 8 + j]);
            o4[g] = pk.u;
        }
    }
}

// =====================================================================
// Kernel 2: dots[b,h] = (K^T V) / n2 ; 4 n-chunks per (b,h), atomicAdd partials
// =====================================================================
__global__ __launch_bounds__(256) void dots_kernel(
    const unsigned short* __restrict__ Kbuf, const unsigned short* __restrict__ Vbuf,
    float* __restrict__ dots)
{
    __shared__ unsigned short kt[64 * 64];
    __shared__ unsigned short vt[64 * 64];
    const int bh = blockIdx.x;
    const int chunk = blockIdx.y;
    const size_t base = ((size_t)bh * NN + (size_t)chunk * 1024) * DH;
    const int tid = threadIdx.x;
    const int d0 = (tid & 15) * 4;
    const int e0 = (tid >> 4) * 4;

    float acc[4][4];
    #pragma unroll
    for (int i = 0; i < 4; ++i)
        #pragma unroll
        for (int j = 0; j < 4; ++j) acc[i][j] = 0.f;

    for (int t = 0; t < 16; ++t) {
        const uint4* kg = (const uint4*)(Kbuf + base + (size_t)t * 64 * DH);
        const uint4* vg = (const uint4*)(Vbuf + base + (size_t)t * 64 * DH);
        uint4* kl = (uint4*)kt; uint4* vl = (uint4*)vt;
        for (int i = tid; i < 512; i += 256) { kl[i] = kg[i]; vl[i] = vg[i]; }
        __syncthreads();
        for (int n = 0; n < 64; ++n) {
            float kf[4], vf[4];
            #pragma unroll
            for (int i = 0; i < 4; ++i) kf[i] = bf2f(kt[n * 64 + d0 + i]);
            #pragma unroll
            for (int i = 0; i < 4; ++i) vf[i] = bf2f(vt[n * 64 + e0 + i]);
            #pragma unroll
            for (int i = 0; i < 4; ++i)
                #pragma unroll
                for (int j = 0; j < 4; ++j)
                    acc[i][j] = fmaf(kf[i], vf[j], acc[i][j]);
        }
        __syncthreads();
    }

    float* dp = dots + (size_t)bh * DH * DH;
    const float sc = 1.f / (float)NN;
    #pragma unroll
    for (int i = 0; i < 4; ++i)
        #pragma unroll
        for (int j = 0; j < 4; ++j)
            atomicAdd(&dp[(d0 + i) * DH + (e0 + j)], acc[i][j] * sc);
}

// =====================================================================
// Kernel 3: q = x@Wq ; rotary(q,x_pos) ; t = q@dots ; out = t@Wout + bout
// Block: 256 threads, 32 x-rows. thread = (row 0..31, head 0..7).
// =====================================================================
__global__ __launch_bounds__(256) void qout_kernel(
    const float* __restrict__ x, const float* __restrict__ x_pos,
    const float* __restrict__ Wq, const float* __restrict__ dots,
    const float* __restrict__ Wout, const float* __restrict__ bout,
    float* __restrict__ out)
{
    __shared__ float smem[32 * 512];   // 64 KB: first x-tile (32x260 padded), later t^T (512x32)
    const int blk = blockIdx.x;
    const int b  = blk >> 7;
    const int r0 = (blk & 127) << 5;
    const int tid = threadIdx.x;

    const float4* xg = (const float4*)(x + ((size_t)b * NN + r0) * DIMc);
    for (int i = tid; i < 32 * 64; i += 256) {
        int r = i >> 6, c4 = i & 63;
        *((float4*)&smem[r * 260 + c4 * 4]) = xg[i];
    }
    __syncthreads();

    const int h   = tid >> 5;   // 0..7
    const int row = tid & 31;   // 0..31
    const float* xr = &smem[row * 260];

    float acc[64];
    #pragma unroll
    for (int j = 0; j < 64; ++j) acc[j] = 0.f;

    for (int kk = 0; kk < DIMc; ++kk) {
        const float xv = xr[kk];
        const float4* w = (const float4*)(Wq + (size_t)kk * INNERc + h * 64);
        #pragma unroll
        for (int j = 0; j < 16; ++j) {
            float4 wv = w[j];
            acc[4*j+0] = fmaf(xv, wv.x, acc[4*j+0]);
            acc[4*j+1] = fmaf(xv, wv.y, acc[4*j+1]);
            acc[4*j+2] = fmaf(xv, wv.z, acc[4*j+2]);
            acc[4*j+3] = fmaf(xv, wv.w, acc[4*j+3]);
        }
    }

    // rotary (no norm on q)
    const int n = r0 + row;
    {
        const float px = x_pos[((size_t)b * NN + n) * 2 + 0] * 64.f;
        const float py = x_pos[((size_t)b * NN + n) * 2 + 1] * 64.f;
        float rot[64];
        #pragma unroll
        for (int j = 0; j < 16; ++j) {
            const float invf = exp2f((float)j * -0.83048202f);
            float sx, cx, sy, cy;
            sincosf(px * invf, &sx, &cx);
            sincosf(py * invf, &sy, &cy);
            rot[j]      = acc[j]      * cx - acc[j + 16] * sx;
            rot[j + 16] = acc[j + 16] * cx + acc[j]      * sx;
            rot[32 + j] = acc[32 + j] * cy - acc[48 + j] * sy;
            rot[48 + j] = acc[48 + j] * cy + acc[32 + j] * sy;
        }
        #pragma unroll
        for (int j = 0; j < 64; ++j) acc[j] = rot[j];
    }

    __syncthreads();   // everyone done reading x-tile; smem will be overwritten with t^T

    // step A: t_seg[e] = sum_d q[d] * dots[b,h][d][e]   (dots pre-scaled by 1/n2)
    // 2 e-chunks of 32 to bound register pressure; write t transposed: smem[i*32+row]
    const float* dp = dots + ((size_t)b * HH + h) * DH * DH;
    #pragma unroll
    for (int ch = 0; ch < 2; ++ch) {
        float ts[32];
        #pragma unroll
        for (int j = 0; j < 32; ++j) ts[j] = 0.f;
        #pragma unroll
        for (int d = 0; d < 64; ++d) {
            const float qd = acc[d];
            const float4* dv = (const float4*)(dp + d * 64 + ch * 32);
            #pragma unroll
            for (int j = 0; j < 8; ++j) {
                float4 v = dv[j];
                ts[4*j+0] = fmaf(qd, v.x, ts[4*j+0]);
                ts[4*j+1] = fmaf(qd, v.y, ts[4*j+1]);
                ts[4*j+2] = fmaf(qd, v.z, ts[4*j+2]);
                ts[4*j+3] = fmaf(qd, v.w, ts[4*j+3]);
            }
        }
        #pragma unroll
        for (int k = 0; k < 32; ++k)
            smem[(h * 64 + ch * 32 + k) * 32 + row] = ts[k];
    }
    __syncthreads();

    // step B: out[row][o] = bout[o] + sum_i t[row][i] * Wout[i][o]
    const int cg = tid & 63;   // col-group of 4 (256/4=64)
    const int rg = tid >> 6;   // 4 row groups of 8 (wave-uniform)
    float4 bo = ((const float4*)bout)[cg];
    float4 a2[8];
    #pragma unroll
    for (int r = 0; r < 8; ++r) a2[r] = bo;

    for (int i = 0; i < INNERc; ++i) {
        float4 wv = ((const float4*)(Wout + (size_t)i * DIMc))[cg];
        #pragma unroll
        for (int r = 0; r < 8; ++r) {
            float tv = smem[i * 32 + rg * 8 + r];   // wave-uniform broadcast
            a2[r].x = fmaf(tv, wv.x, a2[r].x);
            a2[r].y = fmaf(tv, wv.y, a2[r].y);
            a2[r].z = fmaf(tv, wv.z, a2[r].z);
            a2[r].w = fmaf(tv, wv.w, a2[r].w);
        }
    }
    #pragma unroll
    for (int r = 0; r < 8; ++r)
        ((float4*)(out + ((size_t)b * NN + r0 + rg * 8 + r) * DIMc))[cg] = a2[r];
}

extern "C" void kernel_launch(void* const* d_in, const int* in_sizes, int n_in,
                              void* d_out, int out_size, void* d_ws, size_t ws_size,
                              hipStream_t stream) {
    (void)in_sizes; (void)n_in; (void)out_size; (void)ws_size;
    const float* x     = (const float*)d_in[0];
    const float* z     = (const float*)d_in[1];
    const float* x_pos = (const float*)d_in[2];
    const float* z_pos = (const float*)d_in[3];
    const float* Wq    = (const float*)d_in[4];
    const float* Wkv   = (const float*)d_in[5];
    const float* Wout  = (const float*)d_in[6];
    const float* bout  = (const float*)d_in[7];
    float* out = (float*)d_out;

    char* ws = (char*)d_ws;
    const size_t kv_elems = (size_t)BB * HH * NN * DH;        // 16,777,216
    unsigned short* Kbuf = (unsigned short*)ws;
    unsigned short* Vbuf = (unsigned short*)(ws + kv_elems * 2);
    float* dots = (float*)(ws + kv_elems * 4);                // after K+V (bf16)

    hipMemsetAsync(dots, 0, (size_t)BB * HH * DH * DH * sizeof(float), stream);
    kv_kernel<<<dim3(BB * (NN / 32)), dim3(256), 0, stream>>>(z, z_pos, Wkv, Kbuf, Vbuf);
    dots_kernel<<<dim3(BB * HH, 4), dim3(256), 0, stream>>>(Kbuf, Vbuf, dots);
    qout_kernel<<<dim3(BB * (NN / 32)), dim3(256), 0, stream>>>(x, x_pos, Wq, dots, Wout, bout, out);
}

// Round 3
// 429.920 us; speedup vs baseline: 4.0667x; 4.0667x over previous
//
#include <hip/hip_runtime.h>
#include <math.h>

#define BB 8
#define NN 4096
#define DIMc 256
#define HH 8
#define DH 64
#define INNERc 512

typedef unsigned short us;
typedef short s16x8 __attribute__((ext_vector_type(8)));   // 8 bf16 operand (4 VGPRs)
typedef float f32x4 __attribute__((ext_vector_type(4)));   // 16x16 C/D frag

static __device__ __forceinline__ us f2bf(float f) {
    union { float f; unsigned int u; } c; c.f = f;
    unsigned int u = c.u;
    return (us)((u + 0x7fffu + ((u >> 16) & 1u)) >> 16);   // RNE
}

#define MFMA16(a, b, c) __builtin_amdgcn_mfma_f32_16x16x32_bf16((a), (b), (c), 0, 0, 0)

// ---------------------------------------------------------------
// cast kernels
// ---------------------------------------------------------------
__global__ __launch_bounds__(256) void cast_bf16(const float* __restrict__ in,
                                                 us* __restrict__ out, int n4) {
    int idx = blockIdx.x * 256 + threadIdx.x;
    if (idx >= n4) return;
    float4 v = ((const float4*)in)[idx];
    union { us s[4]; uint2 u; } pk;
    pk.s[0] = f2bf(v.x); pk.s[1] = f2bf(v.y); pk.s[2] = f2bf(v.z); pk.s[3] = f2bf(v.w);
    ((uint2*)out)[idx] = pk.u;
}

// out[r][c] = in[c][r]; out is R x C, in row-length = R
__global__ __launch_bounds__(256) void cast_T(const float* __restrict__ in,
                                              us* __restrict__ out, int R, int C) {
    int idx = blockIdx.x * 256 + threadIdx.x;
    if (idx >= R * C) return;
    int r = idx / C, c = idx % C;
    out[idx] = f2bf(in[(size_t)c * R + r]);
}

// dotsT[bh][e][d] = dots[bh][d][e] / NN  (fp32 -> bf16)
__global__ __launch_bounds__(256) void dots_cvt(const float* __restrict__ dots,
                                                us* __restrict__ dotsT) {
    int bh = blockIdx.x, tid = threadIdx.x;
    for (int i = tid; i < 4096; i += 256) {
        int e = i >> 6, d = i & 63;
        dotsT[(size_t)bh * 4096 + i] = f2bf(dots[(size_t)bh * 4096 + d * 64 + e] * (1.f / (float)NN));
    }
}

// ---------------------------------------------------------------
// Kernel: kv = z@Wkv -> instance-norm -> rotary(K) -> Kt/Vt [b,h,d,n] bf16
// grid (mtile 64, slot 16, b 8), 256 thr. slot<8: K head, else V head.
// ---------------------------------------------------------------
__global__ __launch_bounds__(256) void kv_gemm(
    const us* __restrict__ zbf, const float* __restrict__ z_pos,
    const us* __restrict__ WkvT,
    us* __restrict__ Kt, us* __restrict__ Vt)
{
    __shared__ __align__(16) char smem[67584];
    us* Al = (us*)smem;
    us* Bl = Al + 64 * 264;
    const int tid = threadIdx.x;
    const int r0 = blockIdx.x * 64;
    const int slot = blockIdx.y;
    const int b = blockIdx.z;

    const us* Asrc = zbf + ((size_t)b * NN + r0) * DIMc;
    const us* Bsrc = WkvT + (size_t)slot * 64 * DIMc;
    for (int i = tid; i < 2048; i += 256) {
        int row = i >> 5, seg = i & 31;
        *(uint4*)(Al + row * 264 + seg * 8) = *(const uint4*)(Asrc + row * DIMc + seg * 8);
        *(uint4*)(Bl + row * 264 + seg * 8) = *(const uint4*)(Bsrc + row * DIMc + seg * 8);
    }
    __syncthreads();

    const int wave = tid >> 6, lane = tid & 63;
    const int lr = lane & 15, quad = lane >> 4;
    f32x4 z4 = {0.f, 0.f, 0.f, 0.f};
    f32x4 c[4] = {z4, z4, z4, z4};
    for (int kk = 0; kk < 256; kk += 32) {
        s16x8 a = *(const s16x8*)(Al + (wave * 16 + lr) * 264 + kk + quad * 8);
        #pragma unroll
        for (int j = 0; j < 4; ++j) {
            s16x8 bb = *(const s16x8*)(Bl + (j * 16 + lr) * 264 + kk + quad * 8);
            c[j] = MFMA16(a, bb, c[j]);
        }
    }
    __syncthreads();

    float* Cl   = (float*)smem;                 // 64 x 68
    float* mu_s = (float*)(smem + 17408);
    float* rs_s = (float*)(smem + 17664);
    float* cx_s = (float*)(smem + 17920);
    float* sx_s = (float*)(smem + 22016);
    float* cy_s = (float*)(smem + 26112);
    float* sy_s = (float*)(smem + 30208);
    #pragma unroll
    for (int j = 0; j < 4; ++j)
        #pragma unroll
        for (int r = 0; r < 4; ++r)
            Cl[(wave * 16 + quad * 4 + r) * 68 + j * 16 + lr] = c[j][r];
    __syncthreads();

    const bool isK = (slot < 8);
    if (tid < 64) {
        const int row = tid;
        float s0 = 0.f;
        #pragma unroll
        for (int i = 0; i < 16; ++i) {
            float4 v = *(const float4*)(Cl + row * 68 + i * 4);
            s0 += v.x + v.y + v.z + v.w;
        }
        float mu = s0 * (1.f / 64.f);
        float var = 0.f;
        #pragma unroll
        for (int i = 0; i < 16; ++i) {
            float4 v = *(const float4*)(Cl + row * 68 + i * 4);
            float d0 = v.x - mu, d1 = v.y - mu, d2 = v.z - mu, d3 = v.w - mu;
            var += d0 * d0 + d1 * d1 + d2 * d2 + d3 * d3;
        }
        mu_s[row] = mu;
        rs_s[row] = rsqrtf(var * (1.f / 64.f) + 1e-5f);
        if (isK) {
            const float px = z_pos[((size_t)b * NN + r0 + row) * 2 + 0] * 64.f;
            const float py = z_pos[((size_t)b * NN + r0 + row) * 2 + 1] * 64.f;
            #pragma unroll
            for (int j = 0; j < 16; ++j) {
                const float invf = exp2f((float)j * -0.83048202f);  // 10000^(-j/16)
                float sx, cx, sy, cy;
                sincosf(px * invf, &sx, &cx);
                sincosf(py * invf, &sy, &cy);
                cx_s[j * 64 + row] = cx; sx_s[j * 64 + row] = sx;
                cy_s[j * 64 + row] = cy; sy_s[j * 64 + row] = sy;
            }
        }
    }
    __syncthreads();

    const int d = tid & 63, qq = tid >> 6;
    union { us s[16]; uint4 u[2]; } pk;
    #pragma unroll
    for (int r = 0; r < 16; ++r) {
        const int row = qq * 16 + r;
        const float m = mu_s[row], rs = rs_s[row];
        float a0 = (Cl[row * 68 + d] - m) * rs;
        float val = a0;
        if (isK) {
            float a1 = (Cl[row * 68 + (d ^ 16)] - m) * rs;
            float cc, ss;
            if (d < 32) { cc = cx_s[(d & 15) * 64 + row]; ss = sx_s[(d & 15) * 64 + row]; }
            else        { cc = cy_s[(d & 15) * 64 + row]; ss = sy_s[(d & 15) * 64 + row]; }
            val = (d & 16) ? fmaf(a0, cc, a1 * ss) : fmaf(a0, cc, -(a1 * ss));
        }
        pk.s[r] = f2bf(val);
    }
    us* dst = (isK ? Kt : Vt) + (((size_t)b * HH + (slot & 7)) * DH + d) * NN + r0 + qq * 16;
    *(uint4*)dst = pk.u[0];
    *(uint4*)(dst + 8) = pk.u[1];
}

// ---------------------------------------------------------------
// Kernel: q = x@Wq -> rotary -> Q [b,h,n,d] bf16
// grid (mtile 64, h 8, b 8)
// ---------------------------------------------------------------
__global__ __launch_bounds__(256) void q_gemm(
    const us* __restrict__ xbf, const float* __restrict__ x_pos,
    const us* __restrict__ WqT, us* __restrict__ Q)
{
    __shared__ __align__(16) char smem[67584];
    us* Al = (us*)smem;
    us* Bl = Al + 64 * 264;
    const int tid = threadIdx.x;
    const int r0 = blockIdx.x * 64;
    const int h = blockIdx.y;
    const int b = blockIdx.z;

    const us* Asrc = xbf + ((size_t)b * NN + r0) * DIMc;
    const us* Bsrc = WqT + (size_t)h * 64 * DIMc;
    for (int i = tid; i < 2048; i += 256) {
        int row = i >> 5, seg = i & 31;
        *(uint4*)(Al + row * 264 + seg * 8) = *(const uint4*)(Asrc + row * DIMc + seg * 8);
        *(uint4*)(Bl + row * 264 + seg * 8) = *(const uint4*)(Bsrc + row * DIMc + seg * 8);
    }
    __syncthreads();

    const int wave = tid >> 6, lane = tid & 63;
    const int lr = lane & 15, quad = lane >> 4;
    f32x4 z4 = {0.f, 0.f, 0.f, 0.f};
    f32x4 c[4] = {z4, z4, z4, z4};
    for (int kk = 0; kk < 256; kk += 32) {
        s16x8 a = *(const s16x8*)(Al + (wave * 16 + lr) * 264 + kk + quad * 8);
        #pragma unroll
        for (int j = 0; j < 4; ++j) {
            s16x8 bb = *(const s16x8*)(Bl + (j * 16 + lr) * 264 + kk + quad * 8);
            c[j] = MFMA16(a, bb, c[j]);
        }
    }
    __syncthreads();

    float* Cl   = (float*)smem;
    float* cx_s = (float*)(smem + 17920);
    float* sx_s = (float*)(smem + 22016);
    float* cy_s = (float*)(smem + 26112);
    float* sy_s = (float*)(smem + 30208);
    #pragma unroll
    for (int j = 0; j < 4; ++j)
        #pragma unroll
        for (int r = 0; r < 4; ++r)
            Cl[(wave * 16 + quad * 4 + r) * 68 + j * 16 + lr] = c[j][r];
    __syncthreads();

    if (tid < 64) {
        const int row = tid;
        const float px = x_pos[((size_t)b * NN + r0 + row) * 2 + 0] * 64.f;
        const float py = x_pos[((size_t)b * NN + r0 + row) * 2 + 1] * 64.f;
        #pragma unroll
        for (int j = 0; j < 16; ++j) {
            const float invf = exp2f((float)j * -0.83048202f);
            float sx, cx, sy, cy;
            sincosf(px * invf, &sx, &cx);
            sincosf(py * invf, &sy, &cy);
            cx_s[j * 64 + row] = cx; sx_s[j * 64 + row] = sx;
            cy_s[j * 64 + row] = cy; sy_s[j * 64 + row] = sy;
        }
    }
    __syncthreads();

    const int row = tid & 63, qq = tid >> 6;
    union { us s[16]; uint4 u[2]; } pk;
    #pragma unroll
    for (int i = 0; i < 16; ++i) {
        const int d = qq * 16 + i;
        float a0 = Cl[row * 68 + d];
        float a1 = Cl[row * 68 + (d ^ 16)];
        float cc, ss;
        if (d < 32) { cc = cx_s[(d & 15) * 64 + row]; ss = sx_s[(d & 15) * 64 + row]; }
        else        { cc = cy_s[(d & 15) * 64 + row]; ss = sy_s[(d & 15) * 64 + row]; }
        float val = (d & 16) ? fmaf(a0, cc, a1 * ss) : fmaf(a0, cc, -(a1 * ss));
        pk.s[i] = f2bf(val);
    }
    us* dst = Q + (((size_t)b * HH + h) * NN + r0 + row) * DH + qq * 16;
    *(uint4*)dst = pk.u[0];
    *(uint4*)(dst + 8) = pk.u[1];
}

// ---------------------------------------------------------------
// Kernel: dots[bh] += Kt[bh] (64 x n) x Vt[bh]^T  -> fp32 atomic
// grid (bh 64, nsplit 4)
// ---------------------------------------------------------------
__global__ __launch_bounds__(256) void dots_gemm(
    const us* __restrict__ Kt, const us* __restrict__ Vt, float* __restrict__ dots)
{
    __shared__ __align__(16) char smem[67584];
    us* Kl = (us*)smem;
    us* Vl = Kl + 64 * 264;
    const int bh = blockIdx.x;
    const int tid = threadIdx.x;
    const int wave = tid >> 6, lane = tid & 63;
    const int lr = lane & 15, quad = lane >> 4;
    f32x4 z4 = {0.f, 0.f, 0.f, 0.f};
    f32x4 c[4] = {z4, z4, z4, z4};

    for (int ch = 0; ch < 4; ++ch) {
        const size_t nbase = (size_t)blockIdx.y * 1024 + ch * 256;
        for (int i = tid; i < 2048; i += 256) {       // FIX: full 64 x 256 tile (was 1024 -> half-staged, NaN)
            int row = i >> 5, seg = i & 31;
            *(uint4*)(Kl + row * 264 + seg * 8) =
                *(const uint4*)(Kt + ((size_t)bh * DH + row) * NN + nbase + seg * 8);
            *(uint4*)(Vl + row * 264 + seg * 8) =
                *(const uint4*)(Vt + ((size_t)bh * DH + row) * NN + nbase + seg * 8);
        }
        __syncthreads();
        for (int kk = 0; kk < 256; kk += 32) {
            s16x8 a = *(const s16x8*)(Kl + (wave * 16 + lr) * 264 + kk + quad * 8);
            #pragma unroll
            for (int j = 0; j < 4; ++j) {
                s16x8 bb = *(const s16x8*)(Vl + (j * 16 + lr) * 264 + kk + quad * 8);
                c[j] = MFMA16(a, bb, c[j]);
            }
        }
        __syncthreads();
    }
    float* dp = dots + (size_t)bh * DH * DH;
    #pragma unroll
    for (int j = 0; j < 4; ++j)
        #pragma unroll
        for (int r = 0; r < 4; ++r)
            atomicAdd(dp + (wave * 16 + quad * 4 + r) * 64 + j * 16 + lr, c[j][r]);
}

// ---------------------------------------------------------------
// Kernel: T[b,n,h*64+e] = Q[b,h,n,:] @ dotsT[b,h][e][:]^T  (K=64)
// grid (ntile 64, h 8, b 8)
// ---------------------------------------------------------------
__global__ __launch_bounds__(256) void t_gemm(
    const us* __restrict__ Q, const us* __restrict__ dotsT, us* __restrict__ T)
{
    __shared__ __align__(16) char smem[18432];
    us* Al = (us*)smem;
    us* Bl = Al + 64 * 72;
    const int tid = threadIdx.x;
    const int n0 = blockIdx.x * 64;
    const int h = blockIdx.y, b = blockIdx.z;
    const int bh = b * HH + h;

    for (int i = tid; i < 512; i += 256) {
        int row = i >> 3, seg = i & 7;
        *(uint4*)(Al + row * 72 + seg * 8) =
            *(const uint4*)(Q + ((size_t)bh * NN + n0 + row) * DH + seg * 8);
        *(uint4*)(Bl + row * 72 + seg * 8) =
            *(const uint4*)(dotsT + (size_t)bh * DH * DH + row * DH + seg * 8);
    }
    __syncthreads();

    const int wave = tid >> 6, lane = tid & 63;
    const int lr = lane & 15, quad = lane >> 4;
    f32x4 z4 = {0.f, 0.f, 0.f, 0.f};
    f32x4 c[4] = {z4, z4, z4, z4};
    for (int kk = 0; kk < 64; kk += 32) {
        s16x8 a = *(const s16x8*)(Al + (wave * 16 + lr) * 72 + kk + quad * 8);
        #pragma unroll
        for (int j = 0; j < 4; ++j) {
            s16x8 bb = *(const s16x8*)(Bl + (j * 16 + lr) * 72 + kk + quad * 8);
            c[j] = MFMA16(a, bb, c[j]);
        }
    }
    __syncthreads();
    float* Cl = (float*)smem;
    #pragma unroll
    for (int j = 0; j < 4; ++j)
        #pragma unroll
        for (int r = 0; r < 4; ++r)
            Cl[(wave * 16 + quad * 4 + r) * 68 + j * 16 + lr] = c[j][r];
    __syncthreads();

    const int row = tid & 63, qq = tid >> 6;
    union { us s[16]; uint4 u[2]; } pk;
    #pragma unroll
    for (int i = 0; i < 16; ++i) pk.s[i] = f2bf(Cl[row * 68 + qq * 16 + i]);
    us* dst = T + ((size_t)b * NN + n0 + row) * INNERc + h * DH + qq * 16;
    *(uint4*)dst = pk.u[0];
    *(uint4*)(dst + 8) = pk.u[1];
}

// ---------------------------------------------------------------
// Kernel: out = T[32768,512] @ WoutT^T + bout  (fp32 out)
// grid (mtile 512, ntile 4)
// ---------------------------------------------------------------
__global__ __launch_bounds__(256) void out_gemm(
    const us* __restrict__ T, const us* __restrict__ WoutT,
    const float* __restrict__ bout, float* __restrict__ out)
{
    __shared__ __align__(16) char smem[34816];
    us* Al = (us*)smem;
    us* Bl = Al + 64 * 136;
    const int tid = threadIdx.x;
    const int m0 = blockIdx.x * 64;
    const int n0 = blockIdx.y * 64;
    const int wave = tid >> 6, lane = tid & 63;
    const int lr = lane & 15, quad = lane >> 4;
    f32x4 z4 = {0.f, 0.f, 0.f, 0.f};
    f32x4 c[4] = {z4, z4, z4, z4};

    for (int kc = 0; kc < 4; ++kc) {
        for (int i = tid; i < 1024; i += 256) {
            int row = i >> 4, seg = i & 15;
            *(uint4*)(Al + row * 136 + seg * 8) =
                *(const uint4*)(T + ((size_t)m0 + row) * INNERc + kc * 128 + seg * 8);
            *(uint4*)(Bl + row * 136 + seg * 8) =
                *(const uint4*)(WoutT + ((size_t)n0 + row) * INNERc + kc * 128 + seg * 8);
        }
        __syncthreads();
        for (int kk = 0; kk < 128; kk += 32) {
            s16x8 a = *(const s16x8*)(Al + (wave * 16 + lr) * 136 + kk + quad * 8);
            #pragma unroll
            for (int j = 0; j < 4; ++j) {
                s16x8 bb = *(const s16x8*)(Bl + (j * 16 + lr) * 136 + kk + quad * 8);
                c[j] = MFMA16(a, bb, c[j]);
            }
        }
        __syncthreads();
    }
    float* Cl = (float*)smem;
    #pragma unroll
    for (int j = 0; j < 4; ++j)
        #pragma unroll
        for (int r = 0; r < 4; ++r)
            Cl[(wave * 16 + quad * 4 + r) * 68 + j * 16 + lr] = c[j][r];
    __syncthreads();

    const int row = tid & 63, qq = tid >> 6;
    float4 o[4];
    #pragma unroll
    for (int g = 0; g < 4; ++g) {
        float4 v;
        v.x = Cl[row * 68 + qq * 16 + g * 4 + 0] + bout[n0 + qq * 16 + g * 4 + 0];
        v.y = Cl[row * 68 + qq * 16 + g * 4 + 1] + bout[n0 + qq * 16 + g * 4 + 1];
        v.z = Cl[row * 68 + qq * 16 + g * 4 + 2] + bout[n0 + qq * 16 + g * 4 + 2];
        v.w = Cl[row * 68 + qq * 16 + g * 4 + 3] + bout[n0 + qq * 16 + g * 4 + 3];
        o[g] = v;
    }
    float* dst = out + ((size_t)m0 + row) * DIMc + n0 + qq * 16;
    #pragma unroll
    for (int g = 0; g < 4; ++g) *(float4*)(dst + g * 4) = o[g];
}

extern "C" void kernel_launch(void* const* d_in, const int* in_sizes, int n_in,
                              void* d_out, int out_size, void* d_ws, size_t ws_size,
                              hipStream_t stream) {
    (void)in_sizes; (void)n_in; (void)out_size; (void)ws_size;
    const float* x     = (const float*)d_in[0];
    const float* z     = (const float*)d_in[1];
    const float* x_pos = (const float*)d_in[2];
    const float* z_pos = (const float*)d_in[3];
    const float* Wq    = (const float*)d_in[4];
    const float* Wkv   = (const float*)d_in[5];
    const float* Wout  = (const float*)d_in[6];
    const float* bout  = (const float*)d_in[7];
    float* out = (float*)d_out;

    char* ws = (char*)d_ws;
    us*    z_bf  = (us*)(ws + 0);                    // 16,777,216 B
    us*    x_bf  = (us*)(ws + 16777216);             // 16,777,216 B
    us*    Tb    = (us*)(ws + 0);                    // aliases z_bf+x_bf (dead by then)
    us*    WqT   = (us*)(ws + 33554432);             // 262,144 B
    us*    WkvT  = (us*)(ws + 33816576);             // 524,288 B
    us*    WoutT = (us*)(ws + 34340864);             // 262,144 B
    float* dots  = (float*)(ws + 34603008);          // 1,048,576 B
    us*    dotsT = (us*)(ws + 35651584);             // 524,288 B
    us*    Kt    = (us*)(ws + 36175872);             // 33,554,432 B
    us*    Vt    = (us*)(ws + 69730304);             // 33,554,432 B
    us*    Qb    = (us*)(ws + 103284736);            // 33,554,432 B

    cast_bf16<<<8192, 256, 0, stream>>>(z, z_bf, 2097152);
    cast_bf16<<<8192, 256, 0, stream>>>(x, x_bf, 2097152);
    cast_T<<<512, 256, 0, stream>>>(Wq, WqT, 512, 256);
    cast_T<<<1024, 256, 0, stream>>>(Wkv, WkvT, 1024, 256);
    cast_T<<<512, 256, 0, stream>>>(Wout, WoutT, 256, 512);
    hipMemsetAsync(dots, 0, (size_t)64 * 4096 * 4, stream);

    kv_gemm<<<dim3(64, 16, 8), 256, 0, stream>>>(z_bf, z_pos, WkvT, Kt, Vt);
    dots_gemm<<<dim3(64, 4), 256, 0, stream>>>(Kt, Vt, dots);
    dots_cvt<<<64, 256, 0, stream>>>(dots, dotsT);
    q_gemm<<<dim3(64, 8, 8), 256, 0, stream>>>(x_bf, x_pos, WqT, Qb);
    t_gemm<<<dim3(64, 8, 8), 256, 0, stream>>>(Qb, dotsT, Tb);
    out_gemm<<<dim3(512, 4), 256, 0, stream>>>(Tb, WoutT, bout, out);
}

// Round 4
// 316.212 us; speedup vs baseline: 5.5291x; 1.3596x over previous
//
#include <hip/hip_runtime.h>
#include <math.h>

#define BB 8
#define NN 4096
#define DIMc 256
#define HH 8
#define DH 64
#define INNERc 512

typedef unsigned short us;
typedef short s16x8 __attribute__((ext_vector_type(8)));   // 8 bf16 operand (4 VGPRs)
typedef float f32x4 __attribute__((ext_vector_type(4)));   // 16x16 C/D frag

static __device__ __forceinline__ us f2bf(float f) {
    union { float f; unsigned int u; } c; c.f = f;
    unsigned int u = c.u;
    return (us)((u + 0x7fffu + ((u >> 16) & 1u)) >> 16);   // RNE
}

#define MFMA16(a, b, c) __builtin_amdgcn_mfma_f32_16x16x32_bf16((a), (b), (c), 0, 0, 0)

// ---------------------------------------------------------------
// cast kernels
// ---------------------------------------------------------------
__global__ __launch_bounds__(256) void cast_bf16(const float* __restrict__ in,
                                                 us* __restrict__ out, int n4) {
    int idx = blockIdx.x * 256 + threadIdx.x;
    if (idx >= n4) return;
    float4 v = ((const float4*)in)[idx];
    union { us s[4]; uint2 u; } pk;
    pk.s[0] = f2bf(v.x); pk.s[1] = f2bf(v.y); pk.s[2] = f2bf(v.z); pk.s[3] = f2bf(v.w);
    ((uint2*)out)[idx] = pk.u;
}

// out[r][c] = in[c][r]; out is R x C, in row-length = R
__global__ __launch_bounds__(256) void cast_T(const float* __restrict__ in,
                                              us* __restrict__ out, int R, int C) {
    int idx = blockIdx.x * 256 + threadIdx.x;
    if (idx >= R * C) return;
    int r = idx / C, c = idx % C;
    out[idx] = f2bf(in[(size_t)c * R + r]);
}

// dotsT[bh][e][d] = dots[bh][d][e] / NN  (fp32 -> bf16)
__global__ __launch_bounds__(256) void dots_cvt(const float* __restrict__ dots,
                                                us* __restrict__ dotsT) {
    int bh = blockIdx.x, tid = threadIdx.x;
    for (int i = tid; i < 4096; i += 256) {
        int e = i >> 6, d = i & 63;
        dotsT[(size_t)bh * 4096 + i] = f2bf(dots[(size_t)bh * 4096 + d * 64 + e] * (1.f / (float)NN));
    }
}

// ---------------------------------------------------------------
// kv_gemm v2: 128x128 tile of kv = z@Wkv; in-register norm (shuffle);
// rotary via LDS sincos table; transposed store Kt/Vt[b,h,d,n].
// grid (x: b*32+rowtile, y: coltile 0..7 [0-3 K heads, 4-7 V heads])
// ---------------------------------------------------------------
__global__ __launch_bounds__(256) void kv_gemm(
    const us* __restrict__ zbf, const float* __restrict__ z_pos,
    const us* __restrict__ WkvT,
    us* __restrict__ Kt, us* __restrict__ Vt)
{
    __shared__ __align__(16) char smem[36864];
    us* Abuf = (us*)smem;                 // [128][72]
    us* Bbuf = (us*)(smem + 18432);       // [128][72]
    float4* tab = (float4*)smem;          // epilogue: [128 rows][16 freqs] (cx,sx,cy,sy)

    const int tid = threadIdx.x;
    const int b  = blockIdx.x >> 5;
    const int r0 = (blockIdx.x & 31) * 128;
    const int ct = blockIdx.y;
    const bool isK = (ct < 4);

    const int wave = tid >> 6, lane = tid & 63;
    const int lr = lane & 15, quad = lane >> 4;
    const int wr = wave & 1, wc = wave >> 1;   // row-half, col-half of 128x128

    const us* Asrc = zbf + ((size_t)b * NN + r0) * DIMc;
    const us* Bsrc = WkvT + (size_t)ct * 128 * DIMc;

    f32x4 z4 = {0.f, 0.f, 0.f, 0.f};
    f32x4 acc[4][4];
    #pragma unroll
    for (int i = 0; i < 4; ++i)
        #pragma unroll
        for (int j = 0; j < 4; ++j) acc[i][j] = z4;

    for (int kc = 0; kc < 256; kc += 64) {
        for (int i = tid; i < 2048; i += 256) {
            int half = i >> 10, rr = (i & 1023) >> 3, seg = i & 7;
            const us* src = (half ? Bsrc : Asrc) + (size_t)rr * DIMc + kc + seg * 8;
            us* dst = (half ? Bbuf : Abuf) + rr * 72 + seg * 8;
            *(uint4*)dst = *(const uint4*)src;
        }
        __syncthreads();
        #pragma unroll
        for (int ks = 0; ks < 64; ks += 32) {
            s16x8 a[4], bf[4];
            #pragma unroll
            for (int i = 0; i < 4; ++i)
                a[i] = *(const s16x8*)(Abuf + (wr * 64 + i * 16 + lr) * 72 + ks + quad * 8);
            #pragma unroll
            for (int j = 0; j < 4; ++j)
                bf[j] = *(const s16x8*)(Bbuf + (wc * 64 + j * 16 + lr) * 72 + ks + quad * 8);
            #pragma unroll
            for (int i = 0; i < 4; ++i)
                #pragma unroll
                for (int j = 0; j < 4; ++j)
                    acc[i][j] = MFMA16(a[i], bf[j], acc[i][j]);
        }
        __syncthreads();
    }

    // sincos tables over this block's 128 rows (K tiles only)
    if (isK) {
        for (int idx = tid; idx < 2048; idx += 256) {
            int row = idx >> 4, f = idx & 15;
            float invf = exp2f((float)f * -0.83048202f);   // 10000^(-f/16)
            const float* zp = z_pos + ((size_t)b * NN + r0 + row) * 2;
            float sx, cx, sy, cy;
            sincosf(zp[0] * 64.f * invf, &sx, &cx);
            sincosf(zp[1] * 64.f * invf, &sy, &cy);
            tab[row * 16 + f] = float4{cx, sx, cy, sy};
        }
    }
    __syncthreads();

    const int h = (ct & 3) * 2 + wc;
    us* KV = (isK ? Kt : Vt) + ((size_t)b * HH + h) * DH * NN;

    #pragma unroll
    for (int i = 0; i < 4; ++i) {
        // per-row stats over the 64 head cols (4 j-frags x 16 lr lanes)
        float mu_[4], rs_[4];
        #pragma unroll
        for (int r = 0; r < 4; ++r) {
            float s = acc[i][0][r] + acc[i][1][r] + acc[i][2][r] + acc[i][3][r];
            float q2 = acc[i][0][r] * acc[i][0][r] + acc[i][1][r] * acc[i][1][r]
                     + acc[i][2][r] * acc[i][2][r] + acc[i][3][r] * acc[i][3][r];
            s += __shfl_xor(s, 1);  q2 += __shfl_xor(q2, 1);
            s += __shfl_xor(s, 2);  q2 += __shfl_xor(q2, 2);
            s += __shfl_xor(s, 4);  q2 += __shfl_xor(q2, 4);
            s += __shfl_xor(s, 8);  q2 += __shfl_xor(q2, 8);
            float mu = s * (1.f / 64.f);
            float var = q2 * (1.f / 64.f) - mu * mu;
            mu_[r] = mu;
            rs_[r] = rsqrtf(var + 1e-5f);
        }
        float4 tb[4];
        if (isK) {
            #pragma unroll
            for (int r = 0; r < 4; ++r)
                tb[r] = tab[(wr * 64 + i * 16 + quad * 4 + r) * 16 + lr];
        }
        #pragma unroll
        for (int j = 0; j < 4; ++j) {
            union { us s[4]; uint2 u; } pk;
            #pragma unroll
            for (int r = 0; r < 4; ++r) {
                float v0 = (acc[i][j][r] - mu_[r]) * rs_[r];
                if (isK) {
                    float v1 = (acc[i][j ^ 1][r] - mu_[r]) * rs_[r];
                    float cc = (j < 2) ? tb[r].x : tb[r].z;
                    float sn = (j < 2) ? tb[r].y : tb[r].w;
                    v0 = (j & 1) ? fmaf(v0, cc, v1 * sn) : fmaf(v0, cc, -(v1 * sn));
                }
                pk.s[r] = f2bf(v0);
            }
            const int d = j * 16 + lr;
            const int n = r0 + wr * 64 + i * 16 + quad * 4;
            *(uint2*)(KV + (size_t)d * NN + n) = pk.u;
        }
    }
}

// ---------------------------------------------------------------
// dots_gemm: dots[bh] += Kt[bh] x Vt[bh]^T  -> fp32 atomic
// ---------------------------------------------------------------
__global__ __launch_bounds__(256) void dots_gemm(
    const us* __restrict__ Kt, const us* __restrict__ Vt, float* __restrict__ dots)
{
    __shared__ __align__(16) char smem[67584];
    us* Kl = (us*)smem;
    us* Vl = Kl + 64 * 264;
    const int bh = blockIdx.x;
    const int tid = threadIdx.x;
    const int wave = tid >> 6, lane = tid & 63;
    const int lr = lane & 15, quad = lane >> 4;
    f32x4 z4 = {0.f, 0.f, 0.f, 0.f};
    f32x4 c[4] = {z4, z4, z4, z4};

    for (int ch = 0; ch < 4; ++ch) {
        const size_t nbase = (size_t)blockIdx.y * 1024 + ch * 256;
        for (int i = tid; i < 2048; i += 256) {
            int row = i >> 5, seg = i & 31;
            *(uint4*)(Kl + row * 264 + seg * 8) =
                *(const uint4*)(Kt + ((size_t)bh * DH + row) * NN + nbase + seg * 8);
            *(uint4*)(Vl + row * 264 + seg * 8) =
                *(const uint4*)(Vt + ((size_t)bh * DH + row) * NN + nbase + seg * 8);
        }
        __syncthreads();
        for (int kk = 0; kk < 256; kk += 32) {
            s16x8 a = *(const s16x8*)(Kl + (wave * 16 + lr) * 264 + kk + quad * 8);
            #pragma unroll
            for (int j = 0; j < 4; ++j) {
                s16x8 bb = *(const s16x8*)(Vl + (j * 16 + lr) * 264 + kk + quad * 8);
                c[j] = MFMA16(a, bb, c[j]);
            }
        }
        __syncthreads();
    }
    float* dp = dots + (size_t)bh * DH * DH;
    #pragma unroll
    for (int j = 0; j < 4; ++j)
        #pragma unroll
        for (int r = 0; r < 4; ++r)
            atomicAdd(dp + (wave * 16 + quad * 4 + r) * 64 + j * 16 + lr, c[j][r]);
}

// ---------------------------------------------------------------
// qt_gemm: q = x@Wq (128x128 tile) -> rotary -> q-LDS -> C2=dotsT x q^T
// -> T[b,n,h*64+e].  grid (x: b*32+rowtile, y: coltile 0..3 = head pair)
// ---------------------------------------------------------------
__global__ __launch_bounds__(256) void qt_gemm(
    const us* __restrict__ xbf, const float* __restrict__ x_pos,
    const us* __restrict__ WqT, const us* __restrict__ dotsT,
    us* __restrict__ T)
{
    __shared__ __align__(16) char smem[71680];
    us* Abuf = (us*)smem;                  // [128][72] staging
    us* Bbuf = (us*)(smem + 18432);
    us* qlds = (us*)smem;                  // epilogue: per-wave [64 rows][76] bf16 (aliases staging)
    float4* tab = (float4*)(smem + 38912); // [128][16] sincos

    const int tid = threadIdx.x;
    const int b  = blockIdx.x >> 5;
    const int r0 = (blockIdx.x & 31) * 128;
    const int ct = blockIdx.y;

    const int wave = tid >> 6, lane = tid & 63;
    const int lr = lane & 15, quad = lane >> 4;
    const int wr = wave & 1, wc = wave >> 1;

    const us* Asrc = xbf + ((size_t)b * NN + r0) * DIMc;
    const us* Bsrc = WqT + (size_t)ct * 128 * DIMc;

    f32x4 z4 = {0.f, 0.f, 0.f, 0.f};
    f32x4 acc[4][4];
    #pragma unroll
    for (int i = 0; i < 4; ++i)
        #pragma unroll
        for (int j = 0; j < 4; ++j) acc[i][j] = z4;

    for (int kc = 0; kc < 256; kc += 64) {
        for (int i = tid; i < 2048; i += 256) {
            int half = i >> 10, rr = (i & 1023) >> 3, seg = i & 7;
            const us* src = (half ? Bsrc : Asrc) + (size_t)rr * DIMc + kc + seg * 8;
            us* dst = (half ? Bbuf : Abuf) + rr * 72 + seg * 8;
            *(uint4*)dst = *(const uint4*)src;
        }
        __syncthreads();
        #pragma unroll
        for (int ks = 0; ks < 64; ks += 32) {
            s16x8 a[4], bf[4];
            #pragma unroll
            for (int i = 0; i < 4; ++i)
                a[i] = *(const s16x8*)(Abuf + (wr * 64 + i * 16 + lr) * 72 + ks + quad * 8);
            #pragma unroll
            for (int j = 0; j < 4; ++j)
                bf[j] = *(const s16x8*)(Bbuf + (wc * 64 + j * 16 + lr) * 72 + ks + quad * 8);
            #pragma unroll
            for (int i = 0; i < 4; ++i)
                #pragma unroll
                for (int j = 0; j < 4; ++j)
                    acc[i][j] = MFMA16(a[i], bf[j], acc[i][j]);
        }
        __syncthreads();
    }

    // sincos table (all tiles)
    for (int idx = tid; idx < 2048; idx += 256) {
        int row = idx >> 4, f = idx & 15;
        float invf = exp2f((float)f * -0.83048202f);
        const float* xp = x_pos + ((size_t)b * NN + r0 + row) * 2;
        float sx, cx, sy, cy;
        sincosf(xp[0] * 64.f * invf, &sx, &cx);
        sincosf(xp[1] * 64.f * invf, &sy, &cy);
        tab[row * 16 + f] = float4{cx, sx, cy, sy};
    }
    __syncthreads();

    // rotary in regs, write q bf16 to per-wave LDS tile [row][d] stride 76
    us* qw = qlds + wave * 64 * 76;
    #pragma unroll
    for (int i = 0; i < 4; ++i) {
        float4 tb[4];
        #pragma unroll
        for (int r = 0; r < 4; ++r)
            tb[r] = tab[(wr * 64 + i * 16 + quad * 4 + r) * 16 + lr];
        #pragma unroll
        for (int j = 0; j < 4; ++j) {
            const int d = j * 16 + lr;
            #pragma unroll
            for (int r = 0; r < 4; ++r) {
                float v0 = acc[i][j][r];
                float v1 = acc[i][j ^ 1][r];
                float cc = (j < 2) ? tb[r].x : tb[r].z;
                float sn = (j < 2) ? tb[r].y : tb[r].w;
                float val = (j & 1) ? fmaf(v0, cc, v1 * sn) : fmaf(v0, cc, -(v1 * sn));
                qw[(i * 16 + quad * 4 + r) * 76 + d] = f2bf(val);
            }
        }
    }
    __syncthreads();

    // second MFMA: A = dotsT[bh] (global, [e][d]), B = q-LDS ([n][d]) -> C2[e][n]
    const int h = ct * 2 + wc;
    const us* dA = dotsT + ((size_t)b * HH + h) * 4096;
    f32x4 acc2[4][4];
    #pragma unroll
    for (int i = 0; i < 4; ++i)
        #pragma unroll
        for (int j = 0; j < 4; ++j) acc2[i][j] = z4;

    #pragma unroll
    for (int ks = 0; ks < 64; ks += 32) {
        s16x8 a2[4], b2[4];
        #pragma unroll
        for (int i = 0; i < 4; ++i)
            a2[i] = *(const s16x8*)(dA + (i * 16 + lr) * 64 + ks + quad * 8);
        #pragma unroll
        for (int j = 0; j < 4; ++j)
            b2[j] = *(const s16x8*)(qw + (j * 16 + lr) * 76 + ks + quad * 8);
        #pragma unroll
        for (int i = 0; i < 4; ++i)
            #pragma unroll
            for (int j = 0; j < 4; ++j)
                acc2[i][j] = MFMA16(a2[i], b2[j], acc2[i][j]);
    }

    // store T[n][h*64+e]: per frag 4 consecutive e (he) -> uint2
    #pragma unroll
    for (int i = 0; i < 4; ++i)
        #pragma unroll
        for (int j = 0; j < 4; ++j) {
            union { us s[4]; uint2 u; } pk;
            #pragma unroll
            for (int r = 0; r < 4; ++r) pk.s[r] = f2bf(acc2[i][j][r]);
            const size_t n = (size_t)b * NN + r0 + wr * 64 + j * 16 + lr;
            const int he = h * 64 + i * 16 + quad * 4;
            *(uint2*)(T + n * INNERc + he) = pk.u;
        }
}

// ---------------------------------------------------------------
// out_gemm v2: C'[o][n] = WoutT[o][:] . T[n][:] + bout[o], direct float4 store
// grid (x: ntile 0..255, y: otile 0..1)
// ---------------------------------------------------------------
__global__ __launch_bounds__(256) void out_gemm(
    const us* __restrict__ T, const us* __restrict__ WoutT,
    const float* __restrict__ bout, float* __restrict__ out)
{
    __shared__ __align__(16) char smem[36864];
    us* Abuf = (us*)smem;              // WoutT rows (o)
    us* Bbuf = (us*)(smem + 18432);    // T rows (n)
    const int tid = threadIdx.x;
    const int n0 = blockIdx.x * 128;
    const int o0 = blockIdx.y * 128;

    const int wave = tid >> 6, lane = tid & 63;
    const int lr = lane & 15, quad = lane >> 4;
    const int ow = wave & 1, wc = wave >> 1;

    const us* Asrc = WoutT + (size_t)o0 * INNERc;
    const us* Bsrc = T + (size_t)n0 * INNERc;

    f32x4 z4 = {0.f, 0.f, 0.f, 0.f};
    f32x4 acc[4][4];
    #pragma unroll
    for (int i = 0; i < 4; ++i)
        #pragma unroll
        for (int j = 0; j < 4; ++j) acc[i][j] = z4;

    for (int kc = 0; kc < 512; kc += 64) {
        for (int i = tid; i < 2048; i += 256) {
            int half = i >> 10, rr = (i & 1023) >> 3, seg = i & 7;
            const us* src = (half ? Bsrc : Asrc) + (size_t)rr * INNERc + kc + seg * 8;
            us* dst = (half ? Bbuf : Abuf) + rr * 72 + seg * 8;
            *(uint4*)dst = *(const uint4*)src;
        }
        __syncthreads();
        #pragma unroll
        for (int ks = 0; ks < 64; ks += 32) {
            s16x8 a[4], bf[4];
            #pragma unroll
            for (int i = 0; i < 4; ++i)
                a[i] = *(const s16x8*)(Abuf + (ow * 64 + i * 16 + lr) * 72 + ks + quad * 8);
            #pragma unroll
            for (int j = 0; j < 4; ++j)
                bf[j] = *(const s16x8*)(Bbuf + (wc * 64 + j * 16 + lr) * 72 + ks + quad * 8);
            #pragma unroll
            for (int i = 0; i < 4; ++i)
                #pragma unroll
                for (int j = 0; j < 4; ++j)
                    acc[i][j] = MFMA16(a[i], bf[j], acc[i][j]);
        }
        __syncthreads();
    }

    // epilogue: out[n][o] = acc + bout[o]; frag rows = o (4 consecutive) -> float4
    #pragma unroll
    for (int i = 0; i < 4; ++i) {
        const int o = o0 + ow * 64 + i * 16 + quad * 4;
        float4 bv = *(const float4*)(bout + o);
        #pragma unroll
        for (int j = 0; j < 4; ++j) {
            const size_t n = (size_t)n0 + wc * 64 + j * 16 + lr;
            float4 v;
            v.x = acc[i][j][0] + bv.x;
            v.y = acc[i][j][1] + bv.y;
            v.z = acc[i][j][2] + bv.z;
            v.w = acc[i][j][3] + bv.w;
            *(float4*)(out + n * DIMc + o) = v;
        }
    }
}

extern "C" void kernel_launch(void* const* d_in, const int* in_sizes, int n_in,
                              void* d_out, int out_size, void* d_ws, size_t ws_size,
                              hipStream_t stream) {
    (void)in_sizes; (void)n_in; (void)out_size; (void)ws_size;
    const float* x     = (const float*)d_in[0];
    const float* z     = (const float*)d_in[1];
    const float* x_pos = (const float*)d_in[2];
    const float* z_pos = (const float*)d_in[3];
    const float* Wq    = (const float*)d_in[4];
    const float* Wkv   = (const float*)d_in[5];
    const float* Wout  = (const float*)d_in[6];
    const float* bout  = (const float*)d_in[7];
    float* out = (float*)d_out;

    char* ws = (char*)d_ws;
    us*    z_bf  = (us*)(ws + 0);                    // 16 MB
    us*    x_bf  = (us*)(ws + 16777216);             // 16 MB
    us*    WqT   = (us*)(ws + 33554432);             // 256 KB
    us*    WkvT  = (us*)(ws + 33816576);             // 512 KB
    us*    WoutT = (us*)(ws + 34340864);             // 256 KB
    float* dots  = (float*)(ws + 34603008);          // 1 MB
    us*    dotsT = (us*)(ws + 35651584);             // 512 KB
    us*    Kt    = (us*)(ws + 36175872);             // 32 MB
    us*    Vt    = (us*)(ws + 69730304);             // 32 MB
    us*    Tb    = (us*)(ws + 103284736);            // 32 MB (own region: x_bf still live)

    cast_bf16<<<8192, 256, 0, stream>>>(z, z_bf, 2097152);
    cast_bf16<<<8192, 256, 0, stream>>>(x, x_bf, 2097152);
    cast_T<<<512, 256, 0, stream>>>(Wq, WqT, 512, 256);
    cast_T<<<1024, 256, 0, stream>>>(Wkv, WkvT, 1024, 256);
    cast_T<<<512, 256, 0, stream>>>(Wout, WoutT, 256, 512);
    hipMemsetAsync(dots, 0, (size_t)64 * 4096 * 4, stream);

    kv_gemm<<<dim3(256, 8), 256, 0, stream>>>(z_bf, z_pos, WkvT, Kt, Vt);
    dots_gemm<<<dim3(64, 4), 256, 0, stream>>>(Kt, Vt, dots);
    dots_cvt<<<64, 256, 0, stream>>>(dots, dotsT);
    qt_gemm<<<dim3(256, 4), 256, 0, stream>>>(x_bf, x_pos, WqT, dotsT, Tb);
    out_gemm<<<dim3(256, 2), 256, 0, stream>>>(Tb, WoutT, bout, out);
}